// Round 5
// baseline (139.079 us; speedup 1.0000x reference)
//
#include <hip/hip_runtime.h>
#include <math.h>

#define D 768
#define T 128
#define KC 8            // split-K chunks for GEMM1
#define CHUNKK (D / KC) // 96
#define NPROD 96        // 12 oT x KC producers
#define NCONS 144       // 12 oT x 12 iT consumers
#define MAGIC 0x5A5A1234u

// ln(0.9*0.99) = ln(0.891)
#define LN_ETA_DECAY (-0.11541085151132775f)

// ---------------------------------------------------------------------------
// Single fused kernel, 240 blocks x 256 threads.
//  blocks [0,96):   producers — split-K partial GEMM1 P = keys @ W^T.
//                   Write Ppart[kc], fence, set ready[oT][kc] = MAGIC.
//  blocks [96,240): consumers — pre-stage sKs/sC/sB0, spin on ready[oT][*],
//                   combine partials -> errW, GEMM2 G = errW^T @ (2c*keys),
//                   fused W/mW epilogue; iT==0 does b/mb; iT==1 writes loss
//                   partials + lossdone flag; cbid==2 reduces final losses.
// Flags live in poisoned ws (0xAAAAAAAA != MAGIC) -> no zero-init needed.
// Dependency is one-directional (consumers wait on producers only) ->
// deadlock-free regardless of residency; 240 blocks <= 256 CUs anyway.
// ---------------------------------------------------------------------------
__global__ __launch_bounds__(256) void fused_all(
    const float* __restrict__ W,
    const float* __restrict__ bparam,
    const float* __restrict__ keys,
    const float* __restrict__ values,
    const float* __restrict__ mW,
    const float* __restrict__ mb,
    float* __restrict__ W_new,
    float* __restrict__ b_new,
    float* __restrict__ mW_new,
    float* __restrict__ mb_new,
    float* __restrict__ losses,
    float* __restrict__ Ppart,        // [KC][T][D]
    unsigned* __restrict__ ready,     // [12*KC]
    float* __restrict__ lpart,        // [12][T]
    unsigned* __restrict__ lossdone,  // [12]
    float pow_eta_T, float beta_total, float Csum)
{
    __shared__ float smem[16640];   // 66.56 KiB: max(producer 3200, consumer 16640)
    const int bid = blockIdx.x;
    const int tid = threadIdx.x;

    if (bid < NPROD) {
        // ======================= PRODUCER =======================
        float (*sKt)[132] = (float (*)[132])smem;             // [16][132] k-major keys
        float (*sWo)[68]  = (float (*)[68])(smem + 16 * 132); // [16][68]  k-major W
        const int oT = bid / KC, kc = bid % KC;
        const int obase = oT * 64;
        const int kbase = kc * CHUNKK;
        const int ty = tid >> 4;   // t-group (8 t's)
        const int tx = tid & 15;   // o-group (4 o's)

        float acc[8][4];
        #pragma unroll
        for (int j = 0; j < 8; ++j)
            #pragma unroll
            for (int b = 0; b < 4; ++b) acc[j][b] = 0.f;

        for (int c = 0; c < CHUNKK / 16; ++c) {
            const int kb = kbase + c * 16;
            #pragma unroll
            for (int r = 0; r < 2; ++r) {
                const int idx = tid + r * 256;
                const int t = idx >> 2, q = idx & 3;
                float4 g = *reinterpret_cast<const float4*>(keys + t * D + kb + q * 4);
                sKt[q * 4 + 0][t] = g.x;
                sKt[q * 4 + 1][t] = g.y;
                sKt[q * 4 + 2][t] = g.z;
                sKt[q * 4 + 3][t] = g.w;
            }
            {
                const int o = tid >> 2, q = tid & 3;
                float4 g = *reinterpret_cast<const float4*>(W + (obase + o) * D + kb + q * 4);
                sWo[q * 4 + 0][o] = g.x;
                sWo[q * 4 + 1][o] = g.y;
                sWo[q * 4 + 2][o] = g.z;
                sWo[q * 4 + 3][o] = g.w;
            }
            __syncthreads();

            #pragma unroll
            for (int k = 0; k < 16; ++k) {
                float4 a0 = *reinterpret_cast<const float4*>(&sKt[k][ty * 8]);
                float4 a1 = *reinterpret_cast<const float4*>(&sKt[k][ty * 8 + 4]);
                float4 b  = *reinterpret_cast<const float4*>(&sWo[k][tx * 4]);
                const float av[8] = { a0.x, a0.y, a0.z, a0.w, a1.x, a1.y, a1.z, a1.w };
                const float bv[4] = { b.x, b.y, b.z, b.w };
                #pragma unroll
                for (int j = 0; j < 8; ++j)
                    #pragma unroll
                    for (int n = 0; n < 4; ++n) acc[j][n] += av[j] * bv[n];
            }
            __syncthreads();
        }

        float* outp = Ppart + kc * (T * D);
        #pragma unroll
        for (int j = 0; j < 8; ++j) {
            const int t = ty * 8 + j;
            float4 v = { acc[j][0], acc[j][1], acc[j][2], acc[j][3] };
            *reinterpret_cast<float4*>(outp + t * D + obase + tx * 4) = v;
        }
        __threadfence();     // make Ppart visible device-wide (cross-XCD)
        __syncthreads();     // all threads' stores+fences done
        if (tid == 0)
            __hip_atomic_store(&ready[oT * KC + kc], MAGIC,
                               __ATOMIC_RELEASE, __HIP_MEMORY_SCOPE_AGENT);
    } else {
        // ======================= CONSUMER =======================
        const int cbid = bid - NPROD;
        const int oT = cbid / 12, iT = cbid % 12;
        const int obase = oT * 64, ibase = iT * 64;
        float (*sErr)[64] = (float (*)[64])smem;            // [128][64]
        float (*sKs)[64]  = (float (*)[64])(smem + 8192);   // [128][64]
        float* sC  = smem + 16384;                          // [128]
        float* sB0 = smem + 16512;                          // [64]

        if (tid < T)  sC[tid]  = 0.01f * __expf((float)(127 - tid) * LN_ETA_DECAY);
        if (tid < 64) sB0[tid] = bparam[obase + tid];

        // pre-stage sKs = 2*c[t]*keys[t, i-tile] while producers run
        #pragma unroll
        for (int p = 0; p < 8; ++p) {
            const int idx = tid + p * 256;
            const int t = idx >> 4, q = idx & 15;
            const float c2 = 2.f * 0.01f * __expf((float)(127 - t) * LN_ETA_DECAY);
            float4 kv = *reinterpret_cast<const float4*>(keys + t * D + ibase + q * 4);
            kv.x *= c2; kv.y *= c2; kv.z *= c2; kv.w *= c2;
            *reinterpret_cast<float4*>(&sKs[t][q * 4]) = kv;
        }

        // wait for this o-tile's KC partials
        if (tid == 0) {
            #pragma unroll 1
            for (int k = 0; k < KC; ++k) {
                while (__hip_atomic_load(&ready[oT * KC + k], __ATOMIC_ACQUIRE,
                                         __HIP_MEMORY_SCOPE_AGENT) != MAGIC)
                    __builtin_amdgcn_s_sleep(2);
            }
        }
        __syncthreads();
        __threadfence();   // acquire: invalidate stale cached lines before Ppart reads

        // combine partials + subtract V -> sErr
        #pragma unroll
        for (int p = 0; p < 8; ++p) {
            const int idx = tid + p * 256;
            const int t = idx >> 4, q = idx & 15;
            float4 s = { 0.f, 0.f, 0.f, 0.f };
            #pragma unroll
            for (int kc = 0; kc < KC; ++kc) {
                float4 v = *reinterpret_cast<const float4*>(
                    Ppart + kc * (T * D) + t * D + obase + q * 4);
                s.x += v.x; s.y += v.y; s.z += v.z; s.w += v.w;
            }
            float4 vv = *reinterpret_cast<const float4*>(values + t * D + obase + q * 4);
            s.x -= vv.x; s.y -= vv.y; s.z -= vv.z; s.w -= vv.w;
            *reinterpret_cast<float4*>(&sErr[t][q * 4]) = s;
        }
        __syncthreads();

        const int ty = tid >> 4, tx = tid & 15;   // o-group, i-group
        float acc[4][4];
        #pragma unroll
        for (int a = 0; a < 4; ++a)
            #pragma unroll
            for (int b = 0; b < 4; ++b) acc[a][b] = 0.f;

        #pragma unroll 4
        for (int t = 0; t < T; ++t) {
            float4 a = *reinterpret_cast<const float4*>(&sErr[t][ty * 4]);
            float4 b = *reinterpret_cast<const float4*>(&sKs[t][tx * 4]);
            const float av[4] = { a.x, a.y, a.z, a.w };
            const float bv[4] = { b.x, b.y, b.z, b.w };
            #pragma unroll
            for (int aa = 0; aa < 4; ++aa)
                #pragma unroll
                for (int bb = 0; bb < 4; ++bb) acc[aa][bb] += av[aa] * bv[bb];
        }

        // W / mW epilogue
        #pragma unroll
        for (int aa = 0; aa < 4; ++aa) {
            const int o = obase + ty * 4 + aa;
            const int i = ibase + tx * 4;
            float4 mv = *reinterpret_cast<const float4*>(mW + o * D + i);
            float4 wv = *reinterpret_cast<const float4*>(W + o * D + i);
            float4 nm, wn;
            nm.x = pow_eta_T * mv.x - acc[aa][0];
            nm.y = pow_eta_T * mv.y - acc[aa][1];
            nm.z = pow_eta_T * mv.z - acc[aa][2];
            nm.w = pow_eta_T * mv.w - acc[aa][3];
            wn.x = beta_total * wv.x + nm.x;
            wn.y = beta_total * wv.y + nm.y;
            wn.z = beta_total * wv.z + nm.z;
            wn.w = beta_total * wv.w + nm.w;
            *reinterpret_cast<float4*>(mW_new + o * D + i) = nm;
            *reinterpret_cast<float4*>(W_new + o * D + i) = wn;
        }

        // b epilogue (once per o-tile)
        if (iT == 0 && tid < 64) {
            float S = 0.f;
            for (int t = 0; t < T; ++t) S += sC[t] * sErr[t][tid];
            const int o = obase + tid;
            const float nmb = pow_eta_T * mb[o] - 2.f * S - 2.f * Csum * sB0[tid];
            mb_new[o] = nmb;
            b_new[o]  = beta_total * sB0[tid] + nmb;
        }

        // loss partials (once per o-tile): lpart[oT][t] = sum_{o in tile} errb^2
        if (iT == 1) {
            const int t = tid >> 1, h = tid & 1;
            float L = 0.f;
            #pragma unroll 8
            for (int oo = 0; oo < 32; ++oo) {
                const int o = ((h * 32 + oo) + t) & 63;   // skew to dodge bank aliasing
                const float e = sErr[t][o] + sB0[o];
                L += e * e;
            }
            L += __shfl_xor(L, 1, 64);
            if (h == 0) lpart[oT * T + t] = L;
            __threadfence();
            __syncthreads();
            if (tid == 0)
                __hip_atomic_store(&lossdone[oT], MAGIC,
                                   __ATOMIC_RELEASE, __HIP_MEMORY_SCOPE_AGENT);
        }

        // final loss reduction on one designated block
        if (cbid == 2) {
            if (tid == 0) {
                #pragma unroll 1
                for (int k = 0; k < 12; ++k) {
                    while (__hip_atomic_load(&lossdone[k], __ATOMIC_ACQUIRE,
                                             __HIP_MEMORY_SCOPE_AGENT) != MAGIC)
                        __builtin_amdgcn_s_sleep(2);
                }
            }
            __syncthreads();
            __threadfence();
            if (tid < T) {
                float s = 0.f;
                #pragma unroll
                for (int k = 0; k < 12; ++k) s += lpart[k * T + tid];
                losses[tid] = s * (1.f / 768.f);
            }
        }
    }
}

extern "C" void kernel_launch(void* const* d_in, const int* in_sizes, int n_in,
                              void* d_out, int out_size, void* d_ws, size_t ws_size,
                              hipStream_t stream) {
    const float* W      = (const float*)d_in[0];
    const float* bparam = (const float*)d_in[1];
    const float* keys   = (const float*)d_in[2];
    const float* values = (const float*)d_in[3];
    const float* mW     = (const float*)d_in[4];
    const float* mb     = (const float*)d_in[5];

    float* out = (float*)d_out;
    float* W_new  = out;               // 768*768
    float* b_new  = out + 589824;      // 768
    float* mW_new = out + 590592;      // 768*768
    float* mb_new = out + 1180416;     // 768
    float* losses = out + 1181184;     // 128

    float* Ppart        = (float*)d_ws;                 // KC*T*D floats = 3 MiB
    unsigned* ready     = (unsigned*)(Ppart + KC * T * D); // 96 words
    float* lpart        = (float*)(ready + 128);        // 12*T floats (padded start)
    unsigned* lossdone  = (unsigned*)(lpart + 12 * T);  // 12 words

    double cs = 0.0;
    for (int t = 0; t < T; ++t) cs += 0.01 * pow(0.891, 127 - t);
    const float pow_eta_T  = (float)pow(0.9, 128);
    const float beta_total = (float)pow(0.99, 128);
    const float Csum = (float)cs;

    fused_all<<<NPROD + NCONS, 256, 0, stream>>>(
        W, bparam, keys, values, mW, mb,
        W_new, b_new, mW_new, mb_new, losses,
        Ppart, ready, lpart, lossdone,
        pow_eta_T, beta_total, Csum);
}

// Round 6
// 88.766 us; speedup vs baseline: 1.5668x; 1.5668x over previous
//
#include <hip/hip_runtime.h>
#include <math.h>

#define D 768
#define T 128
#define KC 8            // split-K chunks for GEMM1
#define CHUNKK (D / KC) // 96
#define NSUB (CHUNKK / 16) // 6 sub-chunks of 16

// ln(0.9*0.99) = ln(0.891)
#define LN_ETA_DECAY (-0.11541085151132775f)

// ---------------------------------------------------------------------------
// K1: split-K partial GEMM  P = keys @ W^T   (M=128 t, N=768 o, K=768)
// grid = (12 o-tiles, KC k-chunks), 256 threads.
// LDS tiles are K-MAJOR (inner loop = 3x ds_read_b128 + 32 FMA) and the
// global->reg staging is REGISTER DOUBLE-BUFFERED: next sub-chunk's loads
// are issued before the FMA block, so ~1024 FMA cycles hide ~900-cyc HBM.
// Block (0,0) also zeroes losses (k2's atomicAdd target).
// ---------------------------------------------------------------------------
__global__ __launch_bounds__(256) void k1_pgemm(
    const float* __restrict__ W,
    const float* __restrict__ keys,
    float* __restrict__ Ppart,
    float* __restrict__ losses)
{
    __shared__ float sKt[16][132];  // [k][t], pitch 132
    __shared__ float sWo[16][68];   // [k][o], pitch 68

    const int obase = blockIdx.x * 64;
    const int kbase = blockIdx.y * CHUNKK;
    const int tid = threadIdx.x;
    const int ty = tid >> 4;   // t-group (8 t's)
    const int tx = tid & 15;   // o-group (4 o's)
    const int t0 = tid >> 2;   // staging row (0..63)
    const int q0 = tid & 3;    // staging float4-col (0..3)

    if (blockIdx.x == 0 && blockIdx.y == 0 && tid < T) losses[tid] = 0.f;

    float acc[8][4];
    #pragma unroll
    for (int j = 0; j < 8; ++j)
        #pragma unroll
        for (int b = 0; b < 4; ++b) acc[j][b] = 0.f;

    // prologue: load sub-chunk 0 into regs
    float4 gk0 = *reinterpret_cast<const float4*>(keys + t0 * D + kbase + q0 * 4);
    float4 gk1 = *reinterpret_cast<const float4*>(keys + (t0 + 64) * D + kbase + q0 * 4);
    float4 gw  = *reinterpret_cast<const float4*>(W + (obase + t0) * D + kbase + q0 * 4);

    for (int c = 0; c < NSUB; ++c) {
        // regs -> LDS (transposed to k-major)
        sKt[q0 * 4 + 0][t0] = gk0.x;
        sKt[q0 * 4 + 1][t0] = gk0.y;
        sKt[q0 * 4 + 2][t0] = gk0.z;
        sKt[q0 * 4 + 3][t0] = gk0.w;
        sKt[q0 * 4 + 0][t0 + 64] = gk1.x;
        sKt[q0 * 4 + 1][t0 + 64] = gk1.y;
        sKt[q0 * 4 + 2][t0 + 64] = gk1.z;
        sKt[q0 * 4 + 3][t0 + 64] = gk1.w;
        sWo[q0 * 4 + 0][t0] = gw.x;
        sWo[q0 * 4 + 1][t0] = gw.y;
        sWo[q0 * 4 + 2][t0] = gw.z;
        sWo[q0 * 4 + 3][t0] = gw.w;
        __syncthreads();

        // issue NEXT sub-chunk's loads (waited only at next iteration's store)
        if (c + 1 < NSUB) {
            const int kb = kbase + (c + 1) * 16;
            gk0 = *reinterpret_cast<const float4*>(keys + t0 * D + kb + q0 * 4);
            gk1 = *reinterpret_cast<const float4*>(keys + (t0 + 64) * D + kb + q0 * 4);
            gw  = *reinterpret_cast<const float4*>(W + (obase + t0) * D + kb + q0 * 4);
        }

        #pragma unroll
        for (int k = 0; k < 16; ++k) {
            float4 a0 = *reinterpret_cast<const float4*>(&sKt[k][ty * 8]);
            float4 a1 = *reinterpret_cast<const float4*>(&sKt[k][ty * 8 + 4]);
            float4 b  = *reinterpret_cast<const float4*>(&sWo[k][tx * 4]);
            const float av[8] = { a0.x, a0.y, a0.z, a0.w, a1.x, a1.y, a1.z, a1.w };
            const float bv[4] = { b.x, b.y, b.z, b.w };
            #pragma unroll
            for (int j = 0; j < 8; ++j)
                #pragma unroll
                for (int n = 0; n < 4; ++n) acc[j][n] += av[j] * bv[n];
        }
        __syncthreads();
    }

    float* outp = Ppart + blockIdx.y * (T * D);
    #pragma unroll
    for (int j = 0; j < 8; ++j) {
        const int t = ty * 8 + j;
        float4 v = { acc[j][0], acc[j][1], acc[j][2], acc[j][3] };
        *reinterpret_cast<float4*>(outp + t * D + obase + tx * 4) = v;
    }
}

// ---------------------------------------------------------------------------
// K2: combine partials -> errW tile; GEMM2 G = errW^T @ (2c*keys); fused
// W/mW epilogue. The 4.5 MB of mW/W epilogue data is PREFETCHED into
// registers at kernel start so its HBM latency hides under combine+GEMM2.
// iT==0 blocks emit b_new/mb_new; iT==1 blocks add loss partials.
// grid = 144 (12 oT x 12 iT), 256 threads.
// ---------------------------------------------------------------------------
__global__ __launch_bounds__(256) void k2_main(
    const float* __restrict__ Ppart,
    const float* __restrict__ keys,
    const float* __restrict__ values,
    const float* __restrict__ W,
    const float* __restrict__ mW,
    const float* __restrict__ bparam,
    const float* __restrict__ mb,
    float* __restrict__ W_new,
    float* __restrict__ b_new,
    float* __restrict__ mW_new,
    float* __restrict__ mb_new,
    float* __restrict__ losses,
    float pow_eta_T, float beta_total, float Csum)
{
    __shared__ float sErr[T][64];   // errW[t, o-local]
    __shared__ float sKs[T][64];    // 2*c[t]*keys[t, i-local]
    __shared__ float sC[T];         // c[t]
    __shared__ float sB0[64];       // bparam[o-local]

    const int oT = blockIdx.x / 12, iT = blockIdx.x % 12;
    const int obase = oT * 64, ibase = iT * 64;
    const int tid = threadIdx.x;
    const int ty = tid >> 4, tx = tid & 15;   // o-group, i-group

    // ---- epilogue prefetch: issue mW/W loads NOW, consume after GEMM2 ----
    float4 pm[4], pw[4];
    #pragma unroll
    for (int aa = 0; aa < 4; ++aa) {
        const int o = obase + ty * 4 + aa;
        const int i = ibase + tx * 4;
        pm[aa] = *reinterpret_cast<const float4*>(mW + o * D + i);
        pw[aa] = *reinterpret_cast<const float4*>(W + o * D + i);
    }

    if (tid < T)  sC[tid]  = 0.01f * __expf((float)(127 - tid) * LN_ETA_DECAY);
    if (tid < 64) sB0[tid] = bparam[obase + tid];

    // stage sKs = 2*c[t]*keys[t, i-tile]
    #pragma unroll
    for (int p = 0; p < 8; ++p) {
        const int idx = tid + p * 256;
        const int t = idx >> 4, q = idx & 15;
        const float c2 = 2.f * 0.01f * __expf((float)(127 - t) * LN_ETA_DECAY);
        float4 kv = *reinterpret_cast<const float4*>(keys + t * D + ibase + q * 4);
        kv.x *= c2; kv.y *= c2; kv.z *= c2; kv.w *= c2;
        *reinterpret_cast<float4*>(&sKs[t][q * 4]) = kv;
    }

    // combine partials + subtract V -> sErr
    #pragma unroll
    for (int p = 0; p < 8; ++p) {
        const int idx = tid + p * 256;
        const int t = idx >> 4, q = idx & 15;
        float4 s = { 0.f, 0.f, 0.f, 0.f };
        #pragma unroll
        for (int kc = 0; kc < KC; ++kc) {
            float4 v = *reinterpret_cast<const float4*>(
                Ppart + kc * (T * D) + t * D + obase + q * 4);
            s.x += v.x; s.y += v.y; s.z += v.z; s.w += v.w;
        }
        float4 vv = *reinterpret_cast<const float4*>(values + t * D + obase + q * 4);
        s.x -= vv.x; s.y -= vv.y; s.z -= vv.z; s.w -= vv.w;
        *reinterpret_cast<float4*>(&sErr[t][q * 4]) = s;
    }
    __syncthreads();

    float acc[4][4];
    #pragma unroll
    for (int a = 0; a < 4; ++a)
        #pragma unroll
        for (int b = 0; b < 4; ++b) acc[a][b] = 0.f;

    #pragma unroll 4
    for (int t = 0; t < T; ++t) {
        float4 a = *reinterpret_cast<const float4*>(&sErr[t][ty * 4]);
        float4 b = *reinterpret_cast<const float4*>(&sKs[t][tx * 4]);
        const float av[4] = { a.x, a.y, a.z, a.w };
        const float bv[4] = { b.x, b.y, b.z, b.w };
        #pragma unroll
        for (int aa = 0; aa < 4; ++aa)
            #pragma unroll
            for (int bb = 0; bb < 4; ++bb) acc[aa][bb] += av[aa] * bv[bb];
    }

    // W / mW epilogue from prefetched regs
    #pragma unroll
    for (int aa = 0; aa < 4; ++aa) {
        const int o = obase + ty * 4 + aa;
        const int i = ibase + tx * 4;
        float4 nm, wn;
        nm.x = pow_eta_T * pm[aa].x - acc[aa][0];
        nm.y = pow_eta_T * pm[aa].y - acc[aa][1];
        nm.z = pow_eta_T * pm[aa].z - acc[aa][2];
        nm.w = pow_eta_T * pm[aa].w - acc[aa][3];
        wn.x = beta_total * pw[aa].x + nm.x;
        wn.y = beta_total * pw[aa].y + nm.y;
        wn.z = beta_total * pw[aa].z + nm.z;
        wn.w = beta_total * pw[aa].w + nm.w;
        *reinterpret_cast<float4*>(mW_new + o * D + i) = nm;
        *reinterpret_cast<float4*>(W_new + o * D + i) = wn;
    }

    // b epilogue (once per o-tile)
    if (iT == 0 && tid < 64) {
        float S = 0.f;
        for (int t = 0; t < T; ++t) S += sC[t] * sErr[t][tid];
        const int o = obase + tid;
        const float nmb = pow_eta_T * mb[o] - 2.f * S - 2.f * Csum * sB0[tid];
        mb_new[o] = nmb;
        b_new[o]  = beta_total * sB0[tid] + nmb;
    }

    // losses partial (once per o-tile)
    if (iT == 1) {
        const int t = tid >> 1, h = tid & 1;
        float L = 0.f;
        #pragma unroll 8
        for (int oo = 0; oo < 32; ++oo) {
            const int o = ((h * 32 + oo) + t) & 63;   // skew to dodge bank aliasing
            const float e = sErr[t][o] + sB0[o];
            L += e * e;
        }
        L += __shfl_xor(L, 1, 64);
        if (h == 0) atomicAdd(losses + t, L * (1.f / 768.f));
    }
}

extern "C" void kernel_launch(void* const* d_in, const int* in_sizes, int n_in,
                              void* d_out, int out_size, void* d_ws, size_t ws_size,
                              hipStream_t stream) {
    const float* W      = (const float*)d_in[0];
    const float* bparam = (const float*)d_in[1];
    const float* keys   = (const float*)d_in[2];
    const float* values = (const float*)d_in[3];
    const float* mW     = (const float*)d_in[4];
    const float* mb     = (const float*)d_in[5];

    float* out = (float*)d_out;
    float* W_new  = out;               // 768*768
    float* b_new  = out + 589824;      // 768
    float* mW_new = out + 590592;      // 768*768
    float* mb_new = out + 1180416;     // 768
    float* losses = out + 1181184;     // 128

    float* Ppart = (float*)d_ws;       // KC * 128*768 fp32 = 3.1 MB

    double cs = 0.0;
    for (int t = 0; t < T; ++t) cs += 0.01 * pow(0.891, 127 - t);
    const float pow_eta_T  = (float)pow(0.9, 128);
    const float beta_total = (float)pow(0.99, 128);
    const float Csum = (float)cs;

    k1_pgemm<<<dim3(12, KC), 256, 0, stream>>>(W, keys, Ppart, losses);
    k2_main<<<144, 256, 0, stream>>>(Ppart, keys, values, W, mW, bparam, mb,
                                     W_new, b_new, mW_new, mb_new, losses,
                                     pow_eta_T, beta_total, Csum);
}

// Round 7
// 83.546 us; speedup vs baseline: 1.6647x; 1.0625x over previous
//
#include <hip/hip_runtime.h>
#include <math.h>

#define D 768
#define T 128
#define KC 16            // split-K chunks for GEMM1
#define CHUNKK (D / KC)  // 48
#define NSUB (CHUNKK / 16) // 3 sub-chunks of 16

// ln(0.9*0.99) = ln(0.891)
#define LN_ETA_DECAY (-0.11541085151132775f)

// ---------------------------------------------------------------------------
// K1: split-K partial GEMM  P = keys @ W^T   (M=128 t, N=768 o, K=768)
// grid = (12 o-tiles, KC=16 k-chunks) = 192 blocks, 256 threads.
// K-major LDS tiles (3x ds_read_b128 + 32 FMA per k) + register
// double-buffered staging. Block (0,0) zeroes losses (k2's atomic target).
// ---------------------------------------------------------------------------
__global__ __launch_bounds__(256) void k1_pgemm(
    const float* __restrict__ W,
    const float* __restrict__ keys,
    float* __restrict__ Ppart,
    float* __restrict__ losses)
{
    __shared__ float sKt[16][132];  // [k][t], pitch 132
    __shared__ float sWo[16][68];   // [k][o], pitch 68

    const int obase = blockIdx.x * 64;
    const int kbase = blockIdx.y * CHUNKK;
    const int tid = threadIdx.x;
    const int ty = tid >> 4;   // t-group (8 t's)
    const int tx = tid & 15;   // o-group (4 o's)
    const int t0 = tid >> 2;   // staging row (0..63)
    const int q0 = tid & 3;    // staging float4-col (0..3)

    if (blockIdx.x == 0 && blockIdx.y == 0 && tid < T) losses[tid] = 0.f;

    float acc[8][4];
    #pragma unroll
    for (int j = 0; j < 8; ++j)
        #pragma unroll
        for (int b = 0; b < 4; ++b) acc[j][b] = 0.f;

    // prologue: load sub-chunk 0 into regs
    float4 gk0 = *reinterpret_cast<const float4*>(keys + t0 * D + kbase + q0 * 4);
    float4 gk1 = *reinterpret_cast<const float4*>(keys + (t0 + 64) * D + kbase + q0 * 4);
    float4 gw  = *reinterpret_cast<const float4*>(W + (obase + t0) * D + kbase + q0 * 4);

    for (int c = 0; c < NSUB; ++c) {
        // regs -> LDS (transposed to k-major)
        sKt[q0 * 4 + 0][t0] = gk0.x;
        sKt[q0 * 4 + 1][t0] = gk0.y;
        sKt[q0 * 4 + 2][t0] = gk0.z;
        sKt[q0 * 4 + 3][t0] = gk0.w;
        sKt[q0 * 4 + 0][t0 + 64] = gk1.x;
        sKt[q0 * 4 + 1][t0 + 64] = gk1.y;
        sKt[q0 * 4 + 2][t0 + 64] = gk1.z;
        sKt[q0 * 4 + 3][t0 + 64] = gk1.w;
        sWo[q0 * 4 + 0][t0] = gw.x;
        sWo[q0 * 4 + 1][t0] = gw.y;
        sWo[q0 * 4 + 2][t0] = gw.z;
        sWo[q0 * 4 + 3][t0] = gw.w;
        __syncthreads();

        // issue NEXT sub-chunk's loads (consumed at next iteration's store)
        if (c + 1 < NSUB) {
            const int kb = kbase + (c + 1) * 16;
            gk0 = *reinterpret_cast<const float4*>(keys + t0 * D + kb + q0 * 4);
            gk1 = *reinterpret_cast<const float4*>(keys + (t0 + 64) * D + kb + q0 * 4);
            gw  = *reinterpret_cast<const float4*>(W + (obase + t0) * D + kb + q0 * 4);
        }

        #pragma unroll
        for (int k = 0; k < 16; ++k) {
            float4 a0 = *reinterpret_cast<const float4*>(&sKt[k][ty * 8]);
            float4 a1 = *reinterpret_cast<const float4*>(&sKt[k][ty * 8 + 4]);
            float4 b  = *reinterpret_cast<const float4*>(&sWo[k][tx * 4]);
            const float av[8] = { a0.x, a0.y, a0.z, a0.w, a1.x, a1.y, a1.z, a1.w };
            const float bv[4] = { b.x, b.y, b.z, b.w };
            #pragma unroll
            for (int j = 0; j < 8; ++j)
                #pragma unroll
                for (int n = 0; n < 4; ++n) acc[j][n] += av[j] * bv[n];
        }
        __syncthreads();
    }

    float* outp = Ppart + blockIdx.y * (T * D);
    #pragma unroll
    for (int j = 0; j < 8; ++j) {
        const int t = ty * 8 + j;
        float4 v = { acc[j][0], acc[j][1], acc[j][2], acc[j][3] };
        *reinterpret_cast<float4*>(outp + t * D + obase + tx * 4) = v;
    }
}

// ---------------------------------------------------------------------------
// K1.5: errW[t][o] = sum_kc Ppart[kc][t][o] - values[t][o].
// 96 blocks (8 t-chunks x 12 o-chunks of 16t x 64o), 256 threads,
// one float4 per thread, 16 independent partial loads in flight.
// ---------------------------------------------------------------------------
__global__ __launch_bounds__(256) void k15_reduce(
    const float* __restrict__ Ppart,
    const float* __restrict__ values,
    float* __restrict__ errW)
{
    const int tid = threadIdx.x;
    const int t = (blockIdx.x / 12) * 16 + (tid >> 4);
    const int c = (blockIdx.x % 12) * 64 + (tid & 15) * 4;
    const int off = t * D + c;

    float4 vv = *reinterpret_cast<const float4*>(values + off);
    float4 s = { -vv.x, -vv.y, -vv.z, -vv.w };
    #pragma unroll
    for (int kc = 0; kc < KC; ++kc) {
        float4 v = *reinterpret_cast<const float4*>(Ppart + kc * (T * D) + off);
        s.x += v.x; s.y += v.y; s.z += v.z; s.w += v.w;
    }
    *reinterpret_cast<float4*>(errW + off) = s;
}

// ---------------------------------------------------------------------------
// K2: GEMM2 G = errW^T @ (2c*keys) + fused W/mW epilogue (mW/W prefetched
// into regs so their HBM latency hides under staging+GEMM). iT==0 blocks
// emit b_new/mb_new; iT==1 blocks add loss partials (losses zeroed by k1).
// grid = 144 (12 oT x 12 iT), 256 threads.
// ---------------------------------------------------------------------------
__global__ __launch_bounds__(256) void k2_main(
    const float* __restrict__ errW,
    const float* __restrict__ keys,
    const float* __restrict__ W,
    const float* __restrict__ mW,
    const float* __restrict__ bparam,
    const float* __restrict__ mb,
    float* __restrict__ W_new,
    float* __restrict__ b_new,
    float* __restrict__ mW_new,
    float* __restrict__ mb_new,
    float* __restrict__ losses,
    float pow_eta_T, float beta_total, float Csum)
{
    __shared__ float sErr[T][64];   // errW[t, o-local]
    __shared__ float sKs[T][64];    // 2*c[t]*keys[t, i-local]
    __shared__ float sC[T];         // c[t]
    __shared__ float sB0[64];       // bparam[o-local]

    const int oT = blockIdx.x / 12, iT = blockIdx.x % 12;
    const int obase = oT * 64, ibase = iT * 64;
    const int tid = threadIdx.x;
    const int ty = tid >> 4, tx = tid & 15;   // o-group, i-group

    // ---- epilogue prefetch: issue mW/W loads NOW, consume after GEMM2 ----
    float4 pm[4], pw[4];
    #pragma unroll
    for (int aa = 0; aa < 4; ++aa) {
        const int o = obase + ty * 4 + aa;
        const int i = ibase + tx * 4;
        pm[aa] = *reinterpret_cast<const float4*>(mW + o * D + i);
        pw[aa] = *reinterpret_cast<const float4*>(W + o * D + i);
    }

    if (tid < T)  sC[tid]  = 0.01f * __expf((float)(127 - tid) * LN_ETA_DECAY);
    if (tid < 64) sB0[tid] = bparam[obase + tid];

    // stage sErr (direct errW read) and sKs = 2*c[t]*keys[t, i-tile]
    #pragma unroll
    for (int p = 0; p < 8; ++p) {
        const int idx = tid + p * 256;
        const int t = idx >> 4, q = idx & 15;
        float4 ev = *reinterpret_cast<const float4*>(errW + t * D + obase + q * 4);
        *reinterpret_cast<float4*>(&sErr[t][q * 4]) = ev;

        const float c2 = 2.f * 0.01f * __expf((float)(127 - t) * LN_ETA_DECAY);
        float4 kv = *reinterpret_cast<const float4*>(keys + t * D + ibase + q * 4);
        kv.x *= c2; kv.y *= c2; kv.z *= c2; kv.w *= c2;
        *reinterpret_cast<float4*>(&sKs[t][q * 4]) = kv;
    }
    __syncthreads();

    float acc[4][4];
    #pragma unroll
    for (int a = 0; a < 4; ++a)
        #pragma unroll
        for (int b = 0; b < 4; ++b) acc[a][b] = 0.f;

    #pragma unroll 4
    for (int t = 0; t < T; ++t) {
        float4 a = *reinterpret_cast<const float4*>(&sErr[t][ty * 4]);
        float4 b = *reinterpret_cast<const float4*>(&sKs[t][tx * 4]);
        const float av[4] = { a.x, a.y, a.z, a.w };
        const float bv[4] = { b.x, b.y, b.z, b.w };
        #pragma unroll
        for (int aa = 0; aa < 4; ++aa)
            #pragma unroll
            for (int bb = 0; bb < 4; ++bb) acc[aa][bb] += av[aa] * bv[bb];
    }

    // W / mW epilogue from prefetched regs
    #pragma unroll
    for (int aa = 0; aa < 4; ++aa) {
        const int o = obase + ty * 4 + aa;
        const int i = ibase + tx * 4;
        float4 nm, wn;
        nm.x = pow_eta_T * pm[aa].x - acc[aa][0];
        nm.y = pow_eta_T * pm[aa].y - acc[aa][1];
        nm.z = pow_eta_T * pm[aa].z - acc[aa][2];
        nm.w = pow_eta_T * pm[aa].w - acc[aa][3];
        wn.x = beta_total * pw[aa].x + nm.x;
        wn.y = beta_total * pw[aa].y + nm.y;
        wn.z = beta_total * pw[aa].z + nm.z;
        wn.w = beta_total * pw[aa].w + nm.w;
        *reinterpret_cast<float4*>(mW_new + o * D + i) = nm;
        *reinterpret_cast<float4*>(W_new + o * D + i) = wn;
    }

    // b epilogue (once per o-tile)
    if (iT == 0 && tid < 64) {
        float S = 0.f;
        for (int t = 0; t < T; ++t) S += sC[t] * sErr[t][tid];
        const int o = obase + tid;
        const float nmb = pow_eta_T * mb[o] - 2.f * S - 2.f * Csum * sB0[tid];
        mb_new[o] = nmb;
        b_new[o]  = beta_total * sB0[tid] + nmb;
    }

    // losses partial (once per o-tile)
    if (iT == 1) {
        const int t = tid >> 1, h = tid & 1;
        float L = 0.f;
        #pragma unroll 8
        for (int oo = 0; oo < 32; ++oo) {
            const int o = ((h * 32 + oo) + t) & 63;   // skew to dodge bank aliasing
            const float e = sErr[t][o] + sB0[o];
            L += e * e;
        }
        L += __shfl_xor(L, 1, 64);
        if (h == 0) atomicAdd(losses + t, L * (1.f / 768.f));
    }
}

extern "C" void kernel_launch(void* const* d_in, const int* in_sizes, int n_in,
                              void* d_out, int out_size, void* d_ws, size_t ws_size,
                              hipStream_t stream) {
    const float* W      = (const float*)d_in[0];
    const float* bparam = (const float*)d_in[1];
    const float* keys   = (const float*)d_in[2];
    const float* values = (const float*)d_in[3];
    const float* mW     = (const float*)d_in[4];
    const float* mb     = (const float*)d_in[5];

    float* out = (float*)d_out;
    float* W_new  = out;               // 768*768
    float* b_new  = out + 589824;      // 768
    float* mW_new = out + 590592;      // 768*768
    float* mb_new = out + 1180416;     // 768
    float* losses = out + 1181184;     // 128

    float* Ppart = (float*)d_ws;                 // KC*T*D floats = 6.3 MB
    float* errW  = Ppart + KC * T * D;           // T*D floats

    double cs = 0.0;
    for (int t = 0; t < T; ++t) cs += 0.01 * pow(0.891, 127 - t);
    const float pow_eta_T  = (float)pow(0.9, 128);
    const float beta_total = (float)pow(0.99, 128);
    const float Csum = (float)cs;

    k1_pgemm<<<dim3(12, KC), 256, 0, stream>>>(W, keys, Ppart, losses);
    k15_reduce<<<96, 256, 0, stream>>>(Ppart, values, errW);
    k2_main<<<144, 256, 0, stream>>>(errW, keys, W, mW, bparam, mb,
                                     W_new, b_new, mW_new, mb_new, losses,
                                     pow_eta_T, beta_total, Csum);
}